// Round 2
// baseline (229.191 us; speedup 1.0000x reference)
//
#include <hip/hip_runtime.h>

#define Bn 4096
#define Dn 66
#define Hn 512
#define BT 16
#define NT 512

// Cmat[a*Hn + c] = W2[a,c] * M[c,a],  M[c,a] = sum_{i<Dn} W3[c,i] * W1[i,a]
// grid 256 blocks, 2 cols each; W3 col-index is block-uniform -> scalar loads,
// W1/W2/Cmat accesses coalesced over tid (=a).
__global__ __launch_bounds__(256) void k_cmat(
    const float* __restrict__ W1, const float* __restrict__ W2,
    const float* __restrict__ W3, float* __restrict__ Cmat)
{
    const int c0 = blockIdx.x * 2;
    const int a0 = threadIdx.x;          // handles a0 and a0+256
    float m00 = 0.f, m01 = 0.f, m10 = 0.f, m11 = 0.f;
    for (int i = 0; i < Dn; ++i) {
        const float w3a = W3[c0*Dn + i];         // uniform -> s_load
        const float w3b = W3[(c0+1)*Dn + i];     // uniform -> s_load
        const float x0 = W1[i*Hn + a0];          // coalesced
        const float x1 = W1[i*Hn + a0 + 256];
        m00 = fmaf(x0, w3a, m00); m01 = fmaf(x0, w3b, m01);
        m10 = fmaf(x1, w3a, m10); m11 = fmaf(x1, w3b, m11);
    }
    const float2 wlo = *(const float2*)&W2[a0*Hn + c0];
    const float2 whi = *(const float2*)&W2[(a0+256)*Hn + c0];
    float2 olo, ohi;
    olo.x = wlo.x * m00; olo.y = wlo.y * m01;
    ohi.x = whi.x * m10; ohi.y = whi.y * m11;
    *(float2*)&Cmat[a0*Hn + c0] = olo;
    *(float2*)&Cmat[(a0+256)*Hn + c0] = ohi;
}

// Lane tiling: rg = lane&7 owns rows {2rg, 2rg+1}; cg = lane>>3; wave w owns
// cols [w*64, w*64+64): per lane cols cA..cA+3 and cB..cB+3 (cA = w*64+cg*4,
// cB = cA+32). One smem buffer (64 KB), reused: xT -> hs(interleaved h,s') -> hs2+red.
__global__ __launch_bounds__(NT, 2) void k_main(
    const float* __restrict__ xs, const float* __restrict__ tt,
    const float* __restrict__ W1, const float* __restrict__ b1,
    const float* __restrict__ W2, const float* __restrict__ b2,
    const float* __restrict__ W3, const float* __restrict__ b3,
    const float* __restrict__ Cmat, float* __restrict__ out)
{
    __shared__ float smem[16384];   // 64 KB
    const int tid  = threadIdx.x;
    const int lane = tid & 63;
    const int w    = tid >> 6;
    const int rg   = lane & 7;
    const int cg   = lane >> 3;
    const int cA   = w*64 + cg*4;
    const int cB   = cA + 32;
    const int r0   = blockIdx.x * BT;

    // ---- stage x^T: smem[i*16 + r], row 66 = t ----
    for (int idx = tid; idx < 67*BT; idx += NT) {
        const int i = idx >> 4, r = idx & 15;
        smem[idx] = (i < Dn) ? xs[(size_t)(r0+r)*Dn + i] : tt[r0+r];
    }
    __syncthreads();

    // ---- Phase A: z1 tile 2 rows x 8 cols per lane ----
    float z[2][8];
    {
        const float4 bA = *(const float4*)&b1[cA];
        const float4 bB = *(const float4*)&b1[cB];
        const float bb[8] = {bA.x,bA.y,bA.z,bA.w, bB.x,bB.y,bB.z,bB.w};
        #pragma unroll
        for (int j = 0; j < 8; ++j) { z[0][j] = bb[j]; z[1][j] = bb[j]; }
        for (int i = 0; i < 67; ++i) {
            const float2 xf = *(const float2*)&smem[i*BT + 2*rg];  // lane-distinct, conflict-free
            const float4 wA = *(const float4*)&W1[i*Hn + cA];
            const float4 wB = *(const float4*)&W1[i*Hn + cB];
            const float ww[8] = {wA.x,wA.y,wA.z,wA.w, wB.x,wB.y,wB.z,wB.w};
            #pragma unroll
            for (int j = 0; j < 8; ++j) {
                z[0][j] = fmaf(xf.x, ww[j], z[0][j]);
                z[1][j] = fmaf(xf.y, ww[j], z[1][j]);
            }
        }
    }
    __syncthreads();   // xT reads done; smem reusable

    // ---- write hs[a][2r+b]: (h, s') interleaved, stride 32 floats ----
    #pragma unroll
    for (int j = 0; j < 8; ++j) {
        const int col = (j < 4) ? (cA + j) : (cB + j - 4);
        const float z0 = z[0][j], z1v = z[1][j];
        const float sg0 = 1.f/(1.f + __expf(-z0));
        const float sg1 = 1.f/(1.f + __expf(-z1v));
        float4 v;
        v.x = z0 * sg0;
        v.y = sg0 * (1.f + z0 * (1.f - sg0));
        v.z = z1v * sg1;
        v.w = sg1 * (1.f + z1v * (1.f - sg1));
        *(float4*)&smem[col*32 + 4*rg] = v;
    }
    __syncthreads();

    // ---- Phase B: z2 = h1@W2, v = s1'@Cmat; 1 b128 LDS + 4 float4 VMEM per a ----
    float az[2][8], av[2][8];
    #pragma unroll
    for (int j = 0; j < 8; ++j) { az[0][j]=0.f; az[1][j]=0.f; av[0][j]=0.f; av[1][j]=0.f; }
    #pragma unroll 2
    for (int a = 0; a < Hn; ++a) {
        const float4 hs4 = *(const float4*)&smem[a*32 + 4*rg];       // h0,s0,h1,s1 (lane-distinct rows, bcast over cg)
        const float4 w2A = *(const float4*)&W2[(size_t)a*Hn + cA];
        const float4 w2B = *(const float4*)&W2[(size_t)a*Hn + cB];
        const float4 qA  = *(const float4*)&Cmat[(size_t)a*Hn + cA];
        const float4 qB  = *(const float4*)&Cmat[(size_t)a*Hn + cB];
        const float ww[8] = {w2A.x,w2A.y,w2A.z,w2A.w, w2B.x,w2B.y,w2B.z,w2B.w};
        const float qq[8] = {qA.x,qA.y,qA.z,qA.w, qB.x,qB.y,qB.z,qB.w};
        #pragma unroll
        for (int j = 0; j < 8; ++j) {
            az[0][j] = fmaf(hs4.x, ww[j], az[0][j]);
            az[1][j] = fmaf(hs4.z, ww[j], az[1][j]);
            av[0][j] = fmaf(hs4.y, qq[j], av[0][j]);
            av[1][j] = fmaf(hs4.w, qq[j], av[1][j]);
        }
    }
    __syncthreads();   // all hs reads done; smem reusable

    // ---- epilogue: h2, divergence partials ----
    float dp0 = 0.f, dp1 = 0.f;
    float h2v[2][8];
    {
        const float4 bA = *(const float4*)&b2[cA];
        const float4 bB = *(const float4*)&b2[cB];
        const float bb[8] = {bA.x,bA.y,bA.z,bA.w, bB.x,bB.y,bB.z,bB.w};
        #pragma unroll
        for (int j = 0; j < 8; ++j) {
            float zz = az[0][j] + bb[j];
            float sg = 1.f/(1.f + __expf(-zz));
            h2v[0][j] = zz * sg;
            dp0 = fmaf(sg*(1.f + zz*(1.f - sg)), av[0][j], dp0);
            zz = az[1][j] + bb[j];
            sg = 1.f/(1.f + __expf(-zz));
            h2v[1][j] = zz * sg;
            dp1 = fmaf(sg*(1.f + zz*(1.f - sg)), av[1][j], dp1);
        }
    }
    // reduce over col-groups (lane bits 3..5), rows stay in rg
    dp0 += __shfl_xor(dp0, 8, 64); dp0 += __shfl_xor(dp0, 16, 64); dp0 += __shfl_xor(dp0, 32, 64);
    dp1 += __shfl_xor(dp1, 8, 64); dp1 += __shfl_xor(dp1, 16, 64); dp1 += __shfl_xor(dp1, 32, 64);

    // h2 -> hs2[r*514 + c] (smem[0..8224)); wave dp partials -> red (smem[8224..8352))
    #pragma unroll
    for (int j = 0; j < 8; ++j) {
        const int col = (j < 4) ? (cA + j) : (cB + j - 4);
        smem[(2*rg)*514 + col]   = h2v[0][j];
        smem[(2*rg+1)*514 + col] = h2v[1][j];
    }
    if (cg == 0) {
        smem[8224 + w*BT + 2*rg]     = dp0;
        smem[8224 + w*BT + 2*rg + 1] = dp1;
    }
    __syncthreads();

    if (tid < BT) {
        float s = 0.f;
        #pragma unroll
        for (int q = 0; q < 8; ++q) s += smem[8224 + q*BT + tid];
        out[(size_t)Bn*Dn + r0 + tid] = -s;
    }

    // ---- Phase C: out = h2 @ W3 + b3 ----
    {
        const int r  = tid & 15;
        const int jg = tid >> 4;         // 0..31 -> j = jg, jg+32 (+ 64+jg for jg<2)
        const int j1 = jg + 32;
        float a0 = 0.f, a1 = 0.f, a2 = 0.f;
        for (int c = 0; c < Hn; c += 4) {
            const float2 hA = *(const float2*)&smem[r*514 + c];
            const float2 hB = *(const float2*)&smem[r*514 + c + 2];
            const float h0 = hA.x, h1 = hA.y, h2 = hB.x, h3 = hB.y;
            a0 = fmaf(h0, W3[(size_t)(c+0)*Dn + jg], a0);
            a0 = fmaf(h1, W3[(size_t)(c+1)*Dn + jg], a0);
            a0 = fmaf(h2, W3[(size_t)(c+2)*Dn + jg], a0);
            a0 = fmaf(h3, W3[(size_t)(c+3)*Dn + jg], a0);
            a1 = fmaf(h0, W3[(size_t)(c+0)*Dn + j1], a1);
            a1 = fmaf(h1, W3[(size_t)(c+1)*Dn + j1], a1);
            a1 = fmaf(h2, W3[(size_t)(c+2)*Dn + j1], a1);
            a1 = fmaf(h3, W3[(size_t)(c+3)*Dn + j1], a1);
            if (jg < 2) {
                a2 = fmaf(h0, W3[(size_t)(c+0)*Dn + 64 + jg], a2);
                a2 = fmaf(h1, W3[(size_t)(c+1)*Dn + 64 + jg], a2);
                a2 = fmaf(h2, W3[(size_t)(c+2)*Dn + 64 + jg], a2);
                a2 = fmaf(h3, W3[(size_t)(c+3)*Dn + 64 + jg], a2);
            }
        }
        out[(size_t)(r0+r)*Dn + jg] = a0 + b3[jg];
        out[(size_t)(r0+r)*Dn + j1] = a1 + b3[j1];
        if (jg < 2) out[(size_t)(r0+r)*Dn + 64 + jg] = a2 + b3[64 + jg];
    }
}

extern "C" void kernel_launch(void* const* d_in, const int* in_sizes, int n_in,
                              void* d_out, int out_size, void* d_ws, size_t ws_size,
                              hipStream_t stream)
{
    const float* xs = (const float*)d_in[0];
    const float* t  = (const float*)d_in[1];
    const float* W1 = (const float*)d_in[2];
    const float* b1 = (const float*)d_in[3];
    const float* W2 = (const float*)d_in[4];
    const float* b2 = (const float*)d_in[5];
    const float* W3 = (const float*)d_in[6];
    const float* b3 = (const float*)d_in[7];
    float* out  = (float*)d_out;
    float* Cmat = (float*)d_ws;    // Hn*Hn floats = 1 MB

    k_cmat<<<256, 256, 0, stream>>>(W1, W2, W3, Cmat);
    k_main<<<Bn/BT, NT, 0, stream>>>(xs, t, W1, b1, W2, b2, W3, b3, Cmat, out);
}

// Round 3
// 125.696 us; speedup vs baseline: 1.8234x; 1.8234x over previous
//
#include <hip/hip_runtime.h>

#define Bn 4096
#define Dn 66
#define Hn 512
#define BT 16
#define NT 512
#define LDA 520   // ushort stride for 16-row LDS activation tiles (2-way bank alias = free)

typedef __attribute__((ext_vector_type(8))) short short8;
typedef __attribute__((ext_vector_type(4))) float f32x4;

__device__ __forceinline__ unsigned short f2bf(float x) {
    union { float f; unsigned u; } v; v.f = x;
    unsigned r = v.u + 0x7fffu + ((v.u >> 16) & 1u);   // RNE
    return (unsigned short)(r >> 16);
}
__device__ __forceinline__ float bf2f(unsigned short h) {
    union { float f; unsigned u; } v; v.u = ((unsigned)h) << 16; return v.f;
}

// ---------------- prep: Cmat^T bf16 ----------------
// CmT[c][a] = bf16( W2[a,c] * M[c,a] ),  M[c,a] = sum_i W3[c,i]*W1[i,a]
__global__ __launch_bounds__(256) void k_cmat(
    const float* __restrict__ W1, const float* __restrict__ W2,
    const float* __restrict__ W3, unsigned short* __restrict__ CmT)
{
    const int c0 = blockIdx.x * 2;
    const int a0 = threadIdx.x;
    float m00 = 0.f, m01 = 0.f, m10 = 0.f, m11 = 0.f;
    for (int i = 0; i < Dn; ++i) {
        const float w3a = W3[c0*Dn + i];          // block-uniform -> s_load
        const float w3b = W3[(c0+1)*Dn + i];
        const float x0 = W1[i*Hn + a0];           // coalesced
        const float x1 = W1[i*Hn + a0 + 256];
        m00 = fmaf(x0, w3a, m00); m01 = fmaf(x0, w3b, m01);
        m10 = fmaf(x1, w3a, m10); m11 = fmaf(x1, w3b, m11);
    }
    const float2 wlo = *(const float2*)&W2[a0*Hn + c0];
    const float2 whi = *(const float2*)&W2[(a0+256)*Hn + c0];
    CmT[(size_t)c0*Hn + a0]         = f2bf(wlo.x * m00);
    CmT[(size_t)c0*Hn + a0 + 256]   = f2bf(whi.x * m10);
    CmT[(size_t)(c0+1)*Hn + a0]       = f2bf(wlo.y * m01);
    CmT[(size_t)(c0+1)*Hn + a0 + 256] = f2bf(whi.y * m11);
}

// ---------------- prep: W2^T bf16 (64x64 LDS transpose tiles) ----------------
__global__ __launch_bounds__(256) void k_packw2(
    const float* __restrict__ W2, unsigned short* __restrict__ W2T)
{
    __shared__ unsigned short T[64*72];
    const int ab = blockIdx.x & 7, cb = blockIdx.x >> 3;
    const int a0 = ab*64, c0 = cb*64;
    const int ar = threadIdx.x >> 4;          // 0..15
    const int cc = threadIdx.x & 15;          // float4 chunk
    #pragma unroll
    for (int rnd = 0; rnd < 4; ++rnd) {
        const int a = rnd*16 + ar;
        const float4 v = *(const float4*)&W2[(size_t)(a0+a)*Hn + c0 + cc*4];
        T[(cc*4+0)*72 + a] = f2bf(v.x);
        T[(cc*4+1)*72 + a] = f2bf(v.y);
        T[(cc*4+2)*72 + a] = f2bf(v.z);
        T[(cc*4+3)*72 + a] = f2bf(v.w);
    }
    __syncthreads();
    const int c  = threadIdx.x >> 2;          // 0..63
    const int ch = threadIdx.x & 3;           // 16-ushort chunk
    const short8 lo = *(const short8*)&T[c*72 + ch*16];
    const short8 hi = *(const short8*)&T[c*72 + ch*16 + 8];
    *(short8*)&W2T[(size_t)(c0+c)*Hn + a0 + ch*16]     = lo;
    *(short8*)&W2T[(size_t)(c0+c)*Hn + a0 + ch*16 + 8] = hi;
}

// ---------------- prep: W3^T bf16, padded to 80 rows ----------------
__global__ __launch_bounds__(256) void k_packw3(
    const float* __restrict__ W3, unsigned short* __restrict__ W3T)
{
    const int j = blockIdx.x;   // 0..79
    for (int c = threadIdx.x; c < Hn; c += 256)
        W3T[(size_t)j*Hn + c] = (j < Dn) ? f2bf(W3[(size_t)c*Dn + j]) : (unsigned short)0;
}

// ---------------- main ----------------
__global__ __launch_bounds__(NT, 2) void k_main(
    const float* __restrict__ xs, const float* __restrict__ tt,
    const float* __restrict__ W1, const float* __restrict__ b1,
    const float* __restrict__ b2, const float* __restrict__ b3,
    const unsigned short* __restrict__ W2T,
    const unsigned short* __restrict__ CmT,
    const unsigned short* __restrict__ W3T,
    float* __restrict__ out)
{
    __shared__ __align__(16) unsigned short sHhi[16*LDA];  // h1 hi -> h2 hi
    __shared__ __align__(16) unsigned short sHlo[16*LDA];  // h1 lo -> h2 lo
    __shared__ __align__(16) unsigned short sS1 [16*LDA];  // s1' bf16
    __shared__ __align__(16) float sX[67*BT];
    __shared__ float sRed[8*16];

    const int tid  = threadIdx.x;
    const int lane = tid & 63;
    const int w    = tid >> 6;
    const int r0   = blockIdx.x * BT;

    // ---- stage x^T (row 66 = t), fp32 ----
    for (int idx = tid; idx < 67*BT; idx += NT) {
        const int i = idx >> 4, r = idx & 15;
        sX[idx] = (i < Dn) ? xs[(size_t)(r0+r)*Dn + i] : tt[r0+r];
    }
    __syncthreads();

    // ---- Phase A (fp32 VALU): z1, rows {2rg,2rg+1}, cols cA..cA+3 / cB..cB+3 ----
    const int rg = lane & 7, cg = lane >> 3;
    const int cA = w*64 + cg*4, cB = cA + 32;
    {
        float z[2][8];
        const float4 bA4 = *(const float4*)&b1[cA];
        const float4 bB4 = *(const float4*)&b1[cB];
        const float bb[8] = {bA4.x,bA4.y,bA4.z,bA4.w, bB4.x,bB4.y,bB4.z,bB4.w};
        #pragma unroll
        for (int j = 0; j < 8; ++j) { z[0][j] = bb[j]; z[1][j] = bb[j]; }
        for (int i = 0; i < 67; ++i) {
            const float2 xf = *(const float2*)&sX[i*BT + 2*rg];
            const float4 wA = *(const float4*)&W1[(size_t)i*Hn + cA];
            const float4 wB = *(const float4*)&W1[(size_t)i*Hn + cB];
            const float ww[8] = {wA.x,wA.y,wA.z,wA.w, wB.x,wB.y,wB.z,wB.w};
            #pragma unroll
            for (int j = 0; j < 8; ++j) {
                z[0][j] = fmaf(xf.x, ww[j], z[0][j]);
                z[1][j] = fmaf(xf.y, ww[j], z[1][j]);
            }
        }
        // silu + silu' ; split h1 -> hi+lo bf16 ; s1' -> bf16 ; write LDS
        #pragma unroll
        for (int rr = 0; rr < 2; ++rr) {
            const int r = 2*rg + rr;
            ushort4 phi, plo, ps;
            unsigned short* PH = (unsigned short*)&phi;
            unsigned short* PL = (unsigned short*)&plo;
            unsigned short* PS = (unsigned short*)&ps;
            #pragma unroll
            for (int grp = 0; grp < 2; ++grp) {
                #pragma unroll
                for (int j = 0; j < 4; ++j) {
                    const float zv = z[rr][grp*4 + j];
                    const float sg = 1.f / (1.f + __expf(-zv));
                    const float h  = zv * sg;
                    const float sp = sg * (1.f + zv * (1.f - sg));
                    const unsigned short hh = f2bf(h);
                    PH[j] = hh;
                    PL[j] = f2bf(h - bf2f(hh));
                    PS[j] = f2bf(sp);
                }
                const int cbase = grp ? cB : cA;
                *(ushort4*)&sHhi[r*LDA + cbase] = phi;
                *(ushort4*)&sHlo[r*LDA + cbase] = plo;
                *(ushort4*)&sS1 [r*LDA + cbase] = ps;
            }
        }
    }
    __syncthreads();

    // ---- Phase B (MFMA): z2 = h1@W2 + b2 ; v = s1'@Cmat ----
    // frag roles: A: m=lane&15, k=(lane>>4)*8+j ; B: n=lane&15 ; D: col=lane&15, row=(lane>>4)*4+reg
    const int n = lane & 15, kg = lane >> 4;
    f32x4 zac[4], vac[4];
    #pragma unroll
    for (int ti = 0; ti < 4; ++ti) {
        const float bz = b2[w*64 + ti*16 + n];
        zac[ti] = (f32x4){bz, bz, bz, bz};
        vac[ti] = (f32x4){0.f, 0.f, 0.f, 0.f};
    }
    #pragma unroll 4
    for (int ks = 0; ks < 16; ++ks) {
        const int ao = n*LDA + ks*32 + kg*8;
        const short8 ahi = *(const short8*)&sHhi[ao];
        const short8 alo = *(const short8*)&sHlo[ao];
        const short8 as1 = *(const short8*)&sS1 [ao];
        #pragma unroll
        for (int ti = 0; ti < 4; ++ti) {
            const size_t wo = (size_t)(w*64 + ti*16 + n)*Hn + ks*32 + kg*8;
            const short8 wf = *(const short8*)&W2T[wo];
            const short8 qf = *(const short8*)&CmT[wo];
            zac[ti] = __builtin_amdgcn_mfma_f32_16x16x32_bf16(ahi, wf, zac[ti], 0, 0, 0);
            zac[ti] = __builtin_amdgcn_mfma_f32_16x16x32_bf16(alo, wf, zac[ti], 0, 0, 0);
            vac[ti] = __builtin_amdgcn_mfma_f32_16x16x32_bf16(as1, qf, vac[ti], 0, 0, 0);
        }
    }
    __syncthreads();   // all h1/s1 LDS reads done before overwrite

    // ---- epilogue: h2 (hi/lo) back to LDS, divergence partials ----
    float dp[4] = {0.f, 0.f, 0.f, 0.f};
    #pragma unroll
    for (int ti = 0; ti < 4; ++ti) {
        #pragma unroll
        for (int q = 0; q < 4; ++q) {
            const float z2 = zac[ti][q];
            const float sg = 1.f / (1.f + __expf(-z2));
            const float h2 = z2 * sg;
            const float s2p = sg * (1.f + z2 * (1.f - sg));
            dp[q] = fmaf(s2p, vac[ti][q], dp[q]);
            const unsigned short hh = f2bf(h2);
            const int r = kg*4 + q, c = w*64 + ti*16 + n;
            sHhi[r*LDA + c] = hh;
            sHlo[r*LDA + c] = f2bf(h2 - bf2f(hh));
        }
    }
    #pragma unroll
    for (int q = 0; q < 4; ++q) {
        float v = dp[q];
        v += __shfl_xor(v, 1, 64);
        v += __shfl_xor(v, 2, 64);
        v += __shfl_xor(v, 4, 64);
        v += __shfl_xor(v, 8, 64);
        if (n == 0) sRed[w*16 + kg*4 + q] = v;
    }
    __syncthreads();

    if (tid < BT) {
        float s = 0.f;
        #pragma unroll
        for (int q = 0; q < 8; ++q) s += sRed[q*16 + tid];
        out[(size_t)Bn*Dn + r0 + tid] = -s;
    }

    // ---- Phase C (MFMA): out = h2 @ W3 + b3 ; waves 0..4 own 16-col j-tiles ----
    if (w < 5) {
        const int j = w*16 + n;
        const float bj = (j < Dn) ? b3[j] : 0.f;
        f32x4 oac = {bj, bj, bj, bj};
        #pragma unroll 4
        for (int ks = 0; ks < 16; ++ks) {
            const int ao = n*LDA + ks*32 + kg*8;
            const short8 ahi = *(const short8*)&sHhi[ao];
            const short8 alo = *(const short8*)&sHlo[ao];
            const short8 wf  = *(const short8*)&W3T[(size_t)j*Hn + ks*32 + kg*8];
            oac = __builtin_amdgcn_mfma_f32_16x16x32_bf16(ahi, wf, oac, 0, 0, 0);
            oac = __builtin_amdgcn_mfma_f32_16x16x32_bf16(alo, wf, oac, 0, 0, 0);
        }
        if (j < Dn) {
            #pragma unroll
            for (int q = 0; q < 4; ++q)
                out[(size_t)(r0 + kg*4 + q)*Dn + j] = oac[q];
        }
    }
}

extern "C" void kernel_launch(void* const* d_in, const int* in_sizes, int n_in,
                              void* d_out, int out_size, void* d_ws, size_t ws_size,
                              hipStream_t stream)
{
    const float* xs = (const float*)d_in[0];
    const float* t  = (const float*)d_in[1];
    const float* W1 = (const float*)d_in[2];
    const float* b1 = (const float*)d_in[3];
    const float* W2 = (const float*)d_in[4];
    const float* b2 = (const float*)d_in[5];
    const float* W3 = (const float*)d_in[6];
    const float* b3 = (const float*)d_in[7];
    float* out = (float*)d_out;

    unsigned short* W2T = (unsigned short*)d_ws;                       // 512 KB
    unsigned short* CmT = (unsigned short*)((char*)d_ws + 524288);     // 512 KB
    unsigned short* W3T = (unsigned short*)((char*)d_ws + 1048576);    // 80 KB

    k_cmat  <<<256, 256, 0, stream>>>(W1, W2, W3, CmT);
    k_packw2<<<64,  256, 0, stream>>>(W2, W2T);
    k_packw3<<<80,  256, 0, stream>>>(W3, W3T);
    k_main  <<<Bn/BT, NT, 0, stream>>>(xs, t, W1, b1, b2, b3, W2T, CmT, W3T, out);
}